// Round 1
// 461.152 us; speedup vs baseline: 1.0008x; 1.0008x over previous
//
#include <hip/hip_runtime.h>
#include <math.h>

#define TOKENS 16384
#define HIDDEN 4096
#define NE 64
#define KSPLIT 4
#define KRANGE (HIDDEN / KSPLIT)     // 1024
#define KSTEPS (KRANGE / 32)         // 32 K32-steps per wave

#define IDX_OFF 0
#define SC_OFF   (TOKENS * 2)
#define MASK_OFF (TOKENS * 4)
#define AUX_OFF  (MASK_OFF + TOKENS * 2 * NE)   // 2162688

#define KB_TOTAL (HIDDEN / 32)                  // 128 K32-blocks
#define WF_UINT4 (KB_TOTAL * 12 * 64)           // 98304 uint4 = 1.5 MB
#define P_FLOATS ((size_t)KSPLIT * TOKENS * NE) // 4.19M floats = 16.8 MB

typedef __attribute__((ext_vector_type(8))) short bf16x8;
typedef __attribute__((ext_vector_type(4))) float f32x4;
union U16x8 { uint4 u; bf16x8 v; unsigned w[4]; };

#define AS1 __attribute__((address_space(1)))
#define AS3 __attribute__((address_space(3)))

// Exact truncation split: v == hi + mid + lo bit-exactly (top 3 bf16 "digits").
__device__ inline void split3(float v, unsigned short& h, unsigned short& m,
                              unsigned short& l)
{
    const unsigned bu = __float_as_uint(v);
    const float fh = __uint_as_float(bu & 0xffff0000u);
    const float r  = v - fh;                       // exact
    const unsigned br = __float_as_uint(r);
    const float fm = __uint_as_float(br & 0xffff0000u);
    const float r2 = r - fm;                       // exact
    h = (unsigned short)(bu >> 16);
    m = (unsigned short)(br >> 16);
    l = (unsigned short)(__float_as_uint(r2) >> 16);
}

// Pair-packed split (bitwise identical to split3, fewer VALU ops):
// h/m/l each get [lo16 = digit(f0), hi16 = digit(f1)] via v_perm_b32.
__device__ inline void split2pk(float f0, float f1,
                                unsigned& h, unsigned& m, unsigned& l)
{
    const unsigned u0 = __float_as_uint(f0), u1 = __float_as_uint(f1);
    h = __builtin_amdgcn_perm(u1, u0, 0x07060302u);
    const float r0 = f0 - __uint_as_float(u0 & 0xffff0000u);   // exact
    const float r1 = f1 - __uint_as_float(u1 & 0xffff0000u);   // exact
    const unsigned v0 = __float_as_uint(r0), v1 = __float_as_uint(r1);
    m = __builtin_amdgcn_perm(v1, v0, 0x07060302u);
    const float s0 = r0 - __uint_as_float(v0 & 0xffff0000u);   // exact
    const float s1 = r1 - __uint_as_float(v1 & 0xffff0000u);   // exact
    l = __builtin_amdgcn_perm(__float_as_uint(s1), __float_as_uint(s0), 0x07060302u);
}

// Pre-split W into MFMA B-fragment order:
// frag(kb, s, nt): 64 lanes x 16 B; lane holds B[k=kb*32+(lane>>4)*8+j][n=nt*16+(lane&15)]
__global__ void prep_w(const float* __restrict__ Wg, uint4* __restrict__ Wf)
{
    const int kb = blockIdx.x;             // 0..127
    const int nt = threadIdx.x >> 6;       // 0..3
    const int ln = threadIdx.x & 63;
    const int q  = ln >> 4;
    const int n  = nt * 16 + (ln & 15);

    U16x8 H, M, L;
    #pragma unroll
    for (int j = 0; j < 8; ++j) {
        const int k = kb * 32 + q * 8 + j;
        unsigned short h, m, l;
        split3(Wg[(size_t)k * NE + n], h, m, l);
        H.v[j] = (short)h; M.v[j] = (short)m; L.v[j] = (short)l;
    }
    uint4* base = Wf + (size_t)kb * 12 * 64 + ln;
    base[(0 * 4 + nt) * 64] = H.u;
    base[(1 * 4 + nt) * 64] = M.u;
    base[(2 * 4 + nt) * 64] = L.u;
}

// GEMM: wave = 16 tokens x 64 experts, K-split x4, 2 waves/block (32 tokens).
// A is staged global->LDS with global_load_lds (wave-private double buffer, no
// barriers: producer wave == consumer wave). Counted s_waitcnt vmcnt(2) keeps
// the next K-step's 2 stage loads in flight across the whole compute phase.
// LDS layout: per wave 2 bufs x [16 rows][8 granules of 16B]; granule position
// is XOR-swizzled g' = g ^ (row&7) (applied on the GLOBAL source address and on
// the ds_read address; LDS dest stays linear -> conflict-free ds_read_b128).
__global__ __launch_bounds__(128, 4)
void gemm_kernel(const float* __restrict__ x, const uint4* __restrict__ Wf,
                 float* __restrict__ P)
{
    const int lane = threadIdx.x & 63;
    const int wv   = threadIdx.x >> 6;         // 0..1
    const int ks   = blockIdx.x & (KSPLIT - 1);
    const int tb   = blockIdx.x >> 2;          // 0..511
    const int t0w  = tb * 32 + wv * 16;        // this wave's first token
    const int k0   = ks * KRANGE;

    const int q    = lane >> 4;
    const int mrow = lane & 15;

    __shared__ float lds[2 * 2 * 512];         // 2 waves x 2 bufs x 512 floats = 8 KB
    float* lw = lds + wv * 1024;               // wave-private region

    // Staging source (inverse-swizzled): instr i, lane l covers physical granule
    // (row = i*8 + (l>>3), g' = l&7) holding logical granule g = g' ^ (row&7).
    const int srow = lane >> 3;                              // 0..7
    const int gsw  = ((lane & 7) ^ (srow & 7));              // logical granule
    const float* g0 = x + (size_t)(t0w + srow) * HIDDEN + k0 + gsw * 4;
    const float* g1 = g0 + (size_t)8 * HIDDEN;               // rows 8..15 (row&7 identical)

    const uint4* wbase = Wf + (size_t)(k0 >> 5) * 12 * 64 + lane;

    // Swizzled read positions for this lane's A fragment (row = mrow):
    const int p0 = (q * 2 + 0) ^ (mrow & 7);
    const int p1 = (q * 2 + 1) ^ (mrow & 7);

    f32x4 acc[4];
    #pragma unroll
    for (int nt = 0; nt < 4; ++nt) acc[nt] = (f32x4){0.f, 0.f, 0.f, 0.f};

    // Prologue: stage kb=0 into buffer 0 (2 x 1KB per wave).
    __builtin_amdgcn_global_load_lds((const AS1 void*)g0, (AS3 void*)lw,        16, 0, 0);
    __builtin_amdgcn_global_load_lds((const AS1 void*)g1, (AS3 void*)(lw + 256), 16, 0, 0);

    #pragma unroll 2
    for (int kb = 0; kb < KSTEPS; ++kb) {
        const int b = kb & 1;

        // ---- B first: 12 frag loads (so the single counted wait below covers
        //      stage(kb)+B while leaving only stage(kb+1) outstanding) ----
        U16x8 B[3][4];
        const uint4* wb = wbase + (size_t)kb * (12 * 64);
        #pragma unroll
        for (int s = 0; s < 3; ++s)
            #pragma unroll
            for (int nt = 0; nt < 4; ++nt)
                B[s][nt].u = wb[(s * 4 + nt) * 64];

        // ---- stage kb+1 into the other buffer ----
        if (kb + 1 < KSTEPS) {
            const float* s0 = g0 + (kb + 1) * 32;
            const float* s1 = g1 + (kb + 1) * 32;
            float* l0 = lw + (b ^ 1) * 512;
            __builtin_amdgcn_global_load_lds((const AS1 void*)s0, (AS3 void*)l0,        16, 0, 0);
            __builtin_amdgcn_global_load_lds((const AS1 void*)s1, (AS3 void*)(l0 + 256), 16, 0, 0);
        }

        // Drain everything except the 2 newest loads (= stage(kb+1)).
        // stage(kb) can never be among the 2 newest -> LDS read below is safe
        // under any intra-region scheduling order.
        asm volatile("s_waitcnt vmcnt(2)" ::: "memory");
        __builtin_amdgcn_sched_barrier(0);

        // ---- A fragment from LDS (swizzle-matched ds_read_b128 x2) ----
        const float* cb = lw + b * 512 + mrow * 32;
        const float4 alo = *reinterpret_cast<const float4*>(cb + p0 * 4);
        const float4 ahi = *reinterpret_cast<const float4*>(cb + p1 * 4);
        const float a[8] = {alo.x, alo.y, alo.z, alo.w, ahi.x, ahi.y, ahi.z, ahi.w};

        U16x8 Ah, Am, Al;
        #pragma unroll
        for (int j = 0; j < 4; ++j)
            split2pk(a[2 * j], a[2 * j + 1], Ah.w[j], Am.w[j], Al.w[j]);

        // ---- 24 MFMAs: 6 split-products x 4 n-tiles (order unchanged) ----
        #pragma unroll
        for (int nt = 0; nt < 4; ++nt) {
            acc[nt] = __builtin_amdgcn_mfma_f32_16x16x32_bf16(Ah.v, B[0][nt].v, acc[nt], 0, 0, 0);
            acc[nt] = __builtin_amdgcn_mfma_f32_16x16x32_bf16(Ah.v, B[1][nt].v, acc[nt], 0, 0, 0);
            acc[nt] = __builtin_amdgcn_mfma_f32_16x16x32_bf16(Am.v, B[0][nt].v, acc[nt], 0, 0, 0);
            acc[nt] = __builtin_amdgcn_mfma_f32_16x16x32_bf16(Ah.v, B[2][nt].v, acc[nt], 0, 0, 0);
            acc[nt] = __builtin_amdgcn_mfma_f32_16x16x32_bf16(Am.v, B[1][nt].v, acc[nt], 0, 0, 0);
            acc[nt] = __builtin_amdgcn_mfma_f32_16x16x32_bf16(Al.v, B[0][nt].v, acc[nt], 0, 0, 0);
        }
    }

    // C/D layout (m89-verified): token = t0w + q*4 + r, expert = nt*16 + mrow
    float* prow = P + (size_t)ks * TOKENS * NE;
    #pragma unroll
    for (int nt = 0; nt < 4; ++nt)
        #pragma unroll
        for (int r = 0; r < 4; ++r)
            prow[(size_t)(t0w + q * 4 + r) * NE + nt * 16 + mrow] = acc[nt][r];
}

// Finish: sum 4 partials + verified lane=expert epilogue (4 tokens/wave now).
__global__ __launch_bounds__(256, 4)
void finish_kernel(const float* __restrict__ P, const float* __restrict__ bg,
                   float* __restrict__ out, float* __restrict__ gf,
                   float* __restrict__ gm)
{
    const int lane = threadIdx.x & 63;
    const int wv   = threadIdx.x >> 6;
    const int tbase = blockIdx.x * 16 + wv * 4;

    __shared__ float fsh[NE], msh[NE];
    if (threadIdx.x < NE) { fsh[threadIdx.x] = 0.f; msh[threadIdx.x] = 0.f; }
    __syncthreads();

    const float bias = bg[lane];
    float f_acc = 0.f, m_acc = 0.f;

    for (int t = 0; t < 4; ++t) {
        const int tok = tbase + t;
        float v = bias;
        #pragma unroll
        for (int sp = 0; sp < KSPLIT; ++sp)
            v += P[((size_t)sp * TOKENS + tok) * NE + lane];

        // top-1 (value desc, index asc — matches lax.top_k tie-break)
        float v1 = v; int i1 = lane;
        #pragma unroll
        for (int off = 32; off > 0; off >>= 1) {
            const float ov = __shfl_xor(v1, off, 64);
            const int   oi = __shfl_xor(i1, off, 64);
            if (ov > v1 || (ov == v1 && oi < i1)) { v1 = ov; i1 = oi; }
        }
        // top-2
        float v2 = (lane == i1) ? -INFINITY : v; int i2 = lane;
        #pragma unroll
        for (int off = 32; off > 0; off >>= 1) {
            const float ov = __shfl_xor(v2, off, 64);
            const int   oi = __shfl_xor(i2, off, 64);
            if (ov > v2 || (ov == v2 && oi < i2)) { v2 = ov; i2 = oi; }
        }

        // full 64-way softmax (for m_i)
        const float e = expf(v - v1);
        float sm = e;
        #pragma unroll
        for (int off = 32; off > 0; off >>= 1) sm += __shfl_xor(sm, off, 64);
        m_acc += e / sm;
        f_acc += ((lane == i1) ? 1.f : 0.f) + ((lane == i2) ? 1.f : 0.f);

        // softmax over top-2 (max v1 already subtracted)
        const float p  = expf(v2 - v1);
        const float s0 = 1.f / (1.f + p);
        const float s1 = p / (1.f + p);

        if (lane == 0) {
            out[IDX_OFF + tok * 2 + 0] = (float)i1;
            out[IDX_OFF + tok * 2 + 1] = (float)i2;
        } else if (lane == 1) {
            out[SC_OFF + tok * 2 + 0] = s0;
            out[SC_OFF + tok * 2 + 1] = s1;
        }
        out[MASK_OFF + (size_t)tok * 2 * NE + lane]      = (lane == i1) ? 1.f : 0.f;
        out[MASK_OFF + (size_t)tok * 2 * NE + NE + lane] = (lane == i2) ? 1.f : 0.f;
    }

    atomicAdd(&fsh[lane], f_acc);
    atomicAdd(&msh[lane], m_acc);
    __syncthreads();
    if (threadIdx.x < NE) {
        atomicAdd(&gf[threadIdx.x], fsh[threadIdx.x]);
        atomicAdd(&gm[threadIdx.x], msh[threadIdx.x]);
    }
}

// aux_loss = 0.01 * sum(f_i * m_i) / 64
__global__ void aux_kernel(const float* __restrict__ gf,
                           const float* __restrict__ gm,
                           float* __restrict__ out)
{
    const int lane = threadIdx.x;
    const float f = gf[lane] / (float)(TOKENS * 2);
    const float m = gm[lane] / (float)TOKENS;
    float p = f * m;
    #pragma unroll
    for (int off = 32; off > 0; off >>= 1) p += __shfl_xor(p, off, 64);
    if (lane == 0) out[AUX_OFF] = 0.01f * p / (float)NE;
}

extern "C" void kernel_launch(void* const* d_in, const int* in_sizes, int n_in,
                              void* d_out, int out_size, void* d_ws, size_t ws_size,
                              hipStream_t stream)
{
    const float* x  = (const float*)d_in[0];
    const float* Wg = (const float*)d_in[1];
    const float* bg = (const float*)d_in[2];
    float* out = (float*)d_out;

    uint4* Wf = (uint4*)d_ws;                         // 1.5 MB split-W frags
    float* P  = (float*)d_ws + (size_t)WF_UINT4 * 4;  // 16.8 MB partials
    float* gf = P + P_FLOATS;
    float* gm = gf + NE;

    hipMemsetAsync(gf, 0, 2 * NE * sizeof(float), stream);

    prep_w<<<KB_TOTAL, 256, 0, stream>>>(Wg, Wf);
    gemm_kernel<<<(TOKENS / 32) * KSPLIT, 128, 0, stream>>>(x, Wf, P);
    finish_kernel<<<TOKENS / 16, 256, 0, stream>>>(P, bg, out, gf, gm);
    aux_kernel<<<1, 64, 0, stream>>>(gf, gm, out);
}

// Round 2
// 436.971 us; speedup vs baseline: 1.0562x; 1.0553x over previous
//
#include <hip/hip_runtime.h>
#include <math.h>

#define TOKENS 16384
#define HIDDEN 4096
#define NE 64
#define KSPLIT 4
#define KRANGE (HIDDEN / KSPLIT)     // 1024
#define KSTEPS (KRANGE / 32)         // 32 K32-steps per wave

#define IDX_OFF 0
#define SC_OFF   (TOKENS * 2)
#define MASK_OFF (TOKENS * 4)
#define AUX_OFF  (MASK_OFF + TOKENS * 2 * NE)   // 2162688

#define KB_TOTAL (HIDDEN / 32)                  // 128 K32-blocks
#define WF_UINT4 (KB_TOTAL * 12 * 64)           // 98304 uint4 = 1.5 MB
#define P_FLOATS ((size_t)KSPLIT * TOKENS * NE) // 4.19M floats = 16.8 MB

typedef __attribute__((ext_vector_type(8))) short bf16x8;
typedef __attribute__((ext_vector_type(4))) float f32x4;
union U16x8 { uint4 u; bf16x8 v; unsigned w[4]; };

#define AS1 __attribute__((address_space(1)))
#define AS3 __attribute__((address_space(3)))

// Exact truncation split: v == hi + mid + lo bit-exactly (top 3 bf16 "digits").
__device__ inline void split3(float v, unsigned short& h, unsigned short& m,
                              unsigned short& l)
{
    const unsigned bu = __float_as_uint(v);
    const float fh = __uint_as_float(bu & 0xffff0000u);
    const float r  = v - fh;                       // exact
    const unsigned br = __float_as_uint(r);
    const float fm = __uint_as_float(br & 0xffff0000u);
    const float r2 = r - fm;                       // exact
    h = (unsigned short)(bu >> 16);
    m = (unsigned short)(br >> 16);
    l = (unsigned short)(__float_as_uint(r2) >> 16);
}

// Pair-packed split (bitwise identical to split3, fewer VALU ops):
// h/m/l each get [lo16 = digit(f0), hi16 = digit(f1)] via v_perm_b32.
__device__ inline void split2pk(float f0, float f1,
                                unsigned& h, unsigned& m, unsigned& l)
{
    const unsigned u0 = __float_as_uint(f0), u1 = __float_as_uint(f1);
    h = __builtin_amdgcn_perm(u1, u0, 0x07060302u);
    const float r0 = f0 - __uint_as_float(u0 & 0xffff0000u);   // exact
    const float r1 = f1 - __uint_as_float(u1 & 0xffff0000u);   // exact
    const unsigned v0 = __float_as_uint(r0), v1 = __float_as_uint(r1);
    m = __builtin_amdgcn_perm(v1, v0, 0x07060302u);
    const float s0 = r0 - __uint_as_float(v0 & 0xffff0000u);   // exact
    const float s1 = r1 - __uint_as_float(v1 & 0xffff0000u);   // exact
    l = __builtin_amdgcn_perm(__float_as_uint(s1), __float_as_uint(s0), 0x07060302u);
}

// Pre-split W into MFMA B-fragment order:
// frag(kb, s, nt): 64 lanes x 16 B; lane holds B[k=kb*32+(lane>>4)*8+j][n=nt*16+(lane&15)]
__global__ void prep_w(const float* __restrict__ Wg, uint4* __restrict__ Wf)
{
    const int kb = blockIdx.x;             // 0..127
    const int nt = threadIdx.x >> 6;       // 0..3
    const int ln = threadIdx.x & 63;
    const int q  = ln >> 4;
    const int n  = nt * 16 + (ln & 15);

    U16x8 H, M, L;
    #pragma unroll
    for (int j = 0; j < 8; ++j) {
        const int k = kb * 32 + q * 8 + j;
        unsigned short h, m, l;
        split3(Wg[(size_t)k * NE + n], h, m, l);
        H.v[j] = (short)h; M.v[j] = (short)m; L.v[j] = (short)l;
    }
    uint4* base = Wf + (size_t)kb * 12 * 64 + ln;
    base[(0 * 4 + nt) * 64] = H.u;
    base[(1 * 4 + nt) * 64] = M.u;
    base[(2 * 4 + nt) * 64] = L.u;
}

// GEMM: wave = 64 tokens x 64 experts (4 m-frags), KSPLIT x4.
// B staged wave-private into LDS via global_load_lds (fire-and-forget, so the
// 12 staging loads per step batch-issue — no dest VGPRs for the compiler to
// serialize on). Double-buffered, no barriers (producer wave == consumer).
// One counted s_waitcnt vmcnt(20) per step: keeps stage(kb+1)[12] + A(kb+1)[8]
// in flight across the whole compute phase; drains stage(kb) + A(kb).
// A direct-from-global (float4 pairs), prefetched one step in registers.
__global__ __launch_bounds__(128, 2)
void gemm_kernel(const float* __restrict__ x, const uint4* __restrict__ Wf,
                 float* __restrict__ P)
{
    const int lane = threadIdx.x & 63;
    const int wv   = threadIdx.x >> 6;         // 0..1
    const int ks   = blockIdx.x & (KSPLIT - 1);
    const int tb   = blockIdx.x >> 2;          // 0..127
    const int t0w  = tb * 128 + wv * 64;       // this wave's first token
    const int k0   = ks * KRANGE;

    const int q    = lane >> 4;
    const int mrow = lane & 15;

    // [wave][buf][frag][lane] : 2 x 2 x 12 x 64 x 16 B = 48 KB / block.
    // Linear lane-contiguous frags -> global_load_lds dest (base + lane*16)
    // matches ds_read_b128 (lane*16) exactly; conflict-free.
    __shared__ uint4 lds[2][2][12][64];

    const uint4* wsrc = Wf + (size_t)(k0 >> 5) * (12 * 64) + lane;
    const float* arow = x + (size_t)(t0w + mrow) * HIDDEN + k0 + q * 8;

    f32x4 acc[4][4];
    #pragma unroll
    for (int m = 0; m < 4; ++m)
        #pragma unroll
        for (int nt = 0; nt < 4; ++nt) acc[m][nt] = (f32x4){0.f, 0.f, 0.f, 0.f};

    // ---- prologue: stage B(0) into buf 0; load A(0) into registers ----
    #pragma unroll
    for (int i = 0; i < 12; ++i)
        __builtin_amdgcn_global_load_lds((const AS1 void*)(wsrc + i * 64),
                                         (AS3 void*)&lds[wv][0][i][0], 16, 0, 0);
    float4 ac[4][2];
    #pragma unroll
    for (int f = 0; f < 4; ++f) {
        const float* p = arow + (size_t)f * 16 * HIDDEN;
        ac[f][0] = *reinterpret_cast<const float4*>(p);
        ac[f][1] = *reinterpret_cast<const float4*>(p + 4);
    }

    #pragma unroll 2
    for (int kb = 0; kb < KSTEPS; ++kb) {
        const int b  = kb & 1;
        // Last iteration: clamp prefetch (re-stage same data, never read) so
        // the vmcnt arithmetic stays uniform with no branch.
        const int kn = (kb < KSTEPS - 1) ? kb + 1 : kb;

        // Fence: prev iteration's ds_reads of buf b^1 must not sink past this
        // iteration's stage into buf b^1.
        __builtin_amdgcn_sched_barrier(0);

        // ---- stage B(kn) into buf b^1 (12 fire-and-forget loads) ----
        const uint4* ws = wsrc + (size_t)kn * (12 * 64);
        #pragma unroll
        for (int i = 0; i < 12; ++i)
            __builtin_amdgcn_global_load_lds((const AS1 void*)(ws + i * 64),
                                             (AS3 void*)&lds[wv][b ^ 1][i][0], 16, 0, 0);

        // ---- prefetch A(kn) into registers (8 float4 loads) ----
        float4 an[4][2];
        #pragma unroll
        for (int f = 0; f < 4; ++f) {
            const float* p = arow + (size_t)f * 16 * HIDDEN + (size_t)kn * 32;
            an[f][0] = *reinterpret_cast<const float4*>(p);
            an[f][1] = *reinterpret_cast<const float4*>(p + 4);
        }

        // Drain everything except the 20 loads just issued (12 stage + 8 A):
        // retires stage(kb) (LDS ready) and A(kb) (ac registers valid).
        asm volatile("s_waitcnt vmcnt(20)" ::: "memory");
        __builtin_amdgcn_sched_barrier(0);

        // ---- B frags from LDS (12 x ds_read_b128, lane-contiguous) ----
        U16x8 B[12];
        #pragma unroll
        for (int i = 0; i < 12; ++i) B[i].u = lds[wv][b][i][lane];

        // ---- compute: 4 m-frags x (split + 24 MFMAs) ----
        #pragma unroll
        for (int m = 0; m < 4; ++m) {
            const float a[8] = {ac[m][0].x, ac[m][0].y, ac[m][0].z, ac[m][0].w,
                                ac[m][1].x, ac[m][1].y, ac[m][1].z, ac[m][1].w};
            U16x8 Ah, Am, Al;
            #pragma unroll
            for (int j = 0; j < 4; ++j)
                split2pk(a[2 * j], a[2 * j + 1], Ah.w[j], Am.w[j], Al.w[j]);

            #pragma unroll
            for (int nt = 0; nt < 4; ++nt) {
                acc[m][nt] = __builtin_amdgcn_mfma_f32_16x16x32_bf16(Ah.v, B[0 * 4 + nt].v, acc[m][nt], 0, 0, 0);
                acc[m][nt] = __builtin_amdgcn_mfma_f32_16x16x32_bf16(Ah.v, B[1 * 4 + nt].v, acc[m][nt], 0, 0, 0);
                acc[m][nt] = __builtin_amdgcn_mfma_f32_16x16x32_bf16(Am.v, B[0 * 4 + nt].v, acc[m][nt], 0, 0, 0);
                acc[m][nt] = __builtin_amdgcn_mfma_f32_16x16x32_bf16(Ah.v, B[2 * 4 + nt].v, acc[m][nt], 0, 0, 0);
                acc[m][nt] = __builtin_amdgcn_mfma_f32_16x16x32_bf16(Am.v, B[1 * 4 + nt].v, acc[m][nt], 0, 0, 0);
                acc[m][nt] = __builtin_amdgcn_mfma_f32_16x16x32_bf16(Al.v, B[0 * 4 + nt].v, acc[m][nt], 0, 0, 0);
            }
        }

        // rotate A double-buffer
        #pragma unroll
        for (int f = 0; f < 4; ++f) { ac[f][0] = an[f][0]; ac[f][1] = an[f][1]; }
    }

    // C/D layout (m89-verified): token = t0w + m*16 + q*4 + r, expert = nt*16 + mrow
    float* prow = P + (size_t)ks * TOKENS * NE;
    #pragma unroll
    for (int m = 0; m < 4; ++m)
        #pragma unroll
        for (int nt = 0; nt < 4; ++nt)
            #pragma unroll
            for (int r = 0; r < 4; ++r)
                prow[(size_t)(t0w + m * 16 + q * 4 + r) * NE + nt * 16 + mrow] = acc[m][nt][r];
}

// Finish: sum 4 partials + verified lane=expert epilogue (4 tokens/wave).
__global__ __launch_bounds__(256, 4)
void finish_kernel(const float* __restrict__ P, const float* __restrict__ bg,
                   float* __restrict__ out, float* __restrict__ gf,
                   float* __restrict__ gm)
{
    const int lane = threadIdx.x & 63;
    const int wv   = threadIdx.x >> 6;
    const int tbase = blockIdx.x * 16 + wv * 4;

    __shared__ float fsh[NE], msh[NE];
    if (threadIdx.x < NE) { fsh[threadIdx.x] = 0.f; msh[threadIdx.x] = 0.f; }
    __syncthreads();

    const float bias = bg[lane];
    float f_acc = 0.f, m_acc = 0.f;

    for (int t = 0; t < 4; ++t) {
        const int tok = tbase + t;
        float v = bias;
        #pragma unroll
        for (int sp = 0; sp < KSPLIT; ++sp)
            v += P[((size_t)sp * TOKENS + tok) * NE + lane];

        // top-1 (value desc, index asc — matches lax.top_k tie-break)
        float v1 = v; int i1 = lane;
        #pragma unroll
        for (int off = 32; off > 0; off >>= 1) {
            const float ov = __shfl_xor(v1, off, 64);
            const int   oi = __shfl_xor(i1, off, 64);
            if (ov > v1 || (ov == v1 && oi < i1)) { v1 = ov; i1 = oi; }
        }
        // top-2
        float v2 = (lane == i1) ? -INFINITY : v; int i2 = lane;
        #pragma unroll
        for (int off = 32; off > 0; off >>= 1) {
            const float ov = __shfl_xor(v2, off, 64);
            const int   oi = __shfl_xor(i2, off, 64);
            if (ov > v2 || (ov == v2 && oi < i2)) { v2 = ov; i2 = oi; }
        }

        // full 64-way softmax (for m_i)
        const float e = expf(v - v1);
        float sm = e;
        #pragma unroll
        for (int off = 32; off > 0; off >>= 1) sm += __shfl_xor(sm, off, 64);
        m_acc += e / sm;
        f_acc += ((lane == i1) ? 1.f : 0.f) + ((lane == i2) ? 1.f : 0.f);

        // softmax over top-2 (max v1 already subtracted)
        const float p  = expf(v2 - v1);
        const float s0 = 1.f / (1.f + p);
        const float s1 = p / (1.f + p);

        if (lane == 0) {
            out[IDX_OFF + tok * 2 + 0] = (float)i1;
            out[IDX_OFF + tok * 2 + 1] = (float)i2;
        } else if (lane == 1) {
            out[SC_OFF + tok * 2 + 0] = s0;
            out[SC_OFF + tok * 2 + 1] = s1;
        }
        out[MASK_OFF + (size_t)tok * 2 * NE + lane]      = (lane == i1) ? 1.f : 0.f;
        out[MASK_OFF + (size_t)tok * 2 * NE + NE + lane] = (lane == i2) ? 1.f : 0.f;
    }

    atomicAdd(&fsh[lane], f_acc);
    atomicAdd(&msh[lane], m_acc);
    __syncthreads();
    if (threadIdx.x < NE) {
        atomicAdd(&gf[threadIdx.x], fsh[threadIdx.x]);
        atomicAdd(&gm[threadIdx.x], msh[threadIdx.x]);
    }
}

// aux_loss = 0.01 * sum(f_i * m_i) / 64
__global__ void aux_kernel(const float* __restrict__ gf,
                           const float* __restrict__ gm,
                           float* __restrict__ out)
{
    const int lane = threadIdx.x;
    const float f = gf[lane] / (float)(TOKENS * 2);
    const float m = gm[lane] / (float)TOKENS;
    float p = f * m;
    #pragma unroll
    for (int off = 32; off > 0; off >>= 1) p += __shfl_xor(p, off, 64);
    if (lane == 0) out[AUX_OFF] = 0.01f * p / (float)NE;
}

extern "C" void kernel_launch(void* const* d_in, const int* in_sizes, int n_in,
                              void* d_out, int out_size, void* d_ws, size_t ws_size,
                              hipStream_t stream)
{
    const float* x  = (const float*)d_in[0];
    const float* Wg = (const float*)d_in[1];
    const float* bg = (const float*)d_in[2];
    float* out = (float*)d_out;

    uint4* Wf = (uint4*)d_ws;                         // 1.5 MB split-W frags
    float* P  = (float*)d_ws + (size_t)WF_UINT4 * 4;  // 16.8 MB partials
    float* gf = P + P_FLOATS;
    float* gm = gf + NE;

    hipMemsetAsync(gf, 0, 2 * NE * sizeof(float), stream);

    prep_w<<<KB_TOTAL, 256, 0, stream>>>(Wg, Wf);
    gemm_kernel<<<(TOKENS / 128) * KSPLIT, 128, 0, stream>>>(x, Wf, P);
    finish_kernel<<<TOKENS / 16, 256, 0, stream>>>(P, bg, out, gf, gm);
    aux_kernel<<<1, 64, 0, stream>>>(gf, gm, out);
}

// Round 6
// 428.608 us; speedup vs baseline: 1.0768x; 1.0195x over previous
//
#include <hip/hip_runtime.h>
#include <math.h>

#define TOKENS 16384
#define HIDDEN 4096
#define NE 64
#define KSPLIT 4                     // PINNED: KSPLIT=8 changes the K-reduction
                                     // tree -> tie-flip on expert indices
                                     // (rounds 3-5, deterministic absmax 36).
#define KRANGE (HIDDEN / KSPLIT)     // 1024
#define KSTEPS (KRANGE / 32)         // 32 K32-steps per block

#define IDX_OFF 0
#define SC_OFF   (TOKENS * 2)
#define MASK_OFF (TOKENS * 4)
#define AUX_OFF  (MASK_OFF + TOKENS * 2 * NE)   // 2162688

#define KB_TOTAL (HIDDEN / 32)                  // 128 K32-blocks
#define WF_UINT4 (KB_TOTAL * 12 * 64)           // 98304 uint4 = 1.5 MB
#define P_FLOATS ((size_t)KSPLIT * TOKENS * NE) // 4.19M floats = 16.8 MB

typedef __attribute__((ext_vector_type(8))) short bf16x8;
typedef __attribute__((ext_vector_type(4))) float f32x4;
union U16x8 { uint4 u; bf16x8 v; unsigned w[4]; };

#define AS1 __attribute__((address_space(1)))
#define AS3 __attribute__((address_space(3)))

// Exact truncation split: v == hi + mid + lo bit-exactly (top 3 bf16 "digits").
__device__ inline void split3(float v, unsigned short& h, unsigned short& m,
                              unsigned short& l)
{
    const unsigned bu = __float_as_uint(v);
    const float fh = __uint_as_float(bu & 0xffff0000u);
    const float r  = v - fh;                       // exact
    const unsigned br = __float_as_uint(r);
    const float fm = __uint_as_float(br & 0xffff0000u);
    const float r2 = r - fm;                       // exact
    h = (unsigned short)(bu >> 16);
    m = (unsigned short)(br >> 16);
    l = (unsigned short)(__float_as_uint(r2) >> 16);
}

// Pair-packed split (bitwise identical to split3, fewer VALU ops):
// h/m/l each get [lo16 = digit(f0), hi16 = digit(f1)] via v_perm_b32.
__device__ inline void split2pk(float f0, float f1,
                                unsigned& h, unsigned& m, unsigned& l)
{
    const unsigned u0 = __float_as_uint(f0), u1 = __float_as_uint(f1);
    h = __builtin_amdgcn_perm(u1, u0, 0x07060302u);
    const float r0 = f0 - __uint_as_float(u0 & 0xffff0000u);   // exact
    const float r1 = f1 - __uint_as_float(u1 & 0xffff0000u);   // exact
    const unsigned v0 = __float_as_uint(r0), v1 = __float_as_uint(r1);
    m = __builtin_amdgcn_perm(v1, v0, 0x07060302u);
    const float s0 = r0 - __uint_as_float(v0 & 0xffff0000u);   // exact
    const float s1 = r1 - __uint_as_float(v1 & 0xffff0000u);   // exact
    l = __builtin_amdgcn_perm(__float_as_uint(s1), __float_as_uint(s0), 0x07060302u);
}

// Pre-split W into MFMA B-fragment order:
// frag(kb, s, nt): 64 lanes x 16 B; lane holds B[k=kb*32+(lane>>4)*8+j][n=nt*16+(lane&15)]
__global__ void prep_w(const float* __restrict__ Wg, uint4* __restrict__ Wf)
{
    const int kb = blockIdx.x;             // 0..127
    const int nt = threadIdx.x >> 6;       // 0..3
    const int ln = threadIdx.x & 63;
    const int q  = ln >> 4;
    const int n  = nt * 16 + (ln & 15);

    U16x8 H, M, L;
    #pragma unroll
    for (int j = 0; j < 8; ++j) {
        const int k = kb * 32 + q * 8 + j;
        unsigned short h, m, l;
        split3(Wg[(size_t)k * NE + n], h, m, l);
        H.v[j] = (short)h; M.v[j] = (short)m; L.v[j] = (short)l;
    }
    uint4* base = Wf + (size_t)kb * 12 * 64 + ln;
    base[(0 * 4 + nt) * 64] = H.u;
    base[(1 * 4 + nt) * 64] = M.u;
    base[(2 * 4 + nt) * 64] = L.u;
}

// GEMM: block = 4 waves x 32 tokens = 128 tokens, x 64 experts; KSPLIT=4
// (pinned for bitwise numerics). Grid 512 x 256 thr = 2048 waves = 2
// waves/SIMD (round 2 had 1 — its latency bubbles had no cover), 2 blocks/CU
// that barrier independently. ONE shared B double-buffer per block (24 KB),
// staged cooperatively (wave wv stages frags 3wv..3wv+2 via global_load_lds).
// ALL sync is plain __syncthreads() (m97-canonical): the compiler's barrier
// drain (s_waitcnt vmcnt(0) lgkmcnt(0); s_barrier) covers stage->read (RAW)
// and read->restage (WAR) on both buffers. No inline asm, no counted waits.
// Per-token K accumulation: 32 sequential K32-steps, 6-product order --
// bitwise identical to the round-0/2 passing kernels.
__global__ __launch_bounds__(256, 2)
void gemm_kernel(const float* __restrict__ x, const uint4* __restrict__ Wf,
                 float* __restrict__ P)
{
    const int lane = threadIdx.x & 63;
    const int wv   = threadIdx.x >> 6;         // 0..3
    const int ks   = blockIdx.x & (KSPLIT - 1);
    const int tb   = blockIdx.x >> 2;          // 0..127
    const int t0w  = tb * 128 + wv * 32;       // this wave's first token
    const int k0   = ks * KRANGE;

    const int q    = lane >> 4;
    const int mrow = lane & 15;

    // [buf][frag][lane] : 2 x 12 x 64 x 16 B = 24 KB, shared by all 4 waves.
    // Linear lane-contiguous frags: global_load_lds dest (base + lane*16)
    // matches ds_read (lane*16) exactly; conflict-free.
    __shared__ uint4 lds[2][12][64];

    const uint4* wsrc = Wf + (size_t)(k0 >> 5) * (12 * 64) + lane;
    const float* arow = x + (size_t)(t0w + mrow) * HIDDEN + k0 + q * 8;

    f32x4 acc[2][4];
    #pragma unroll
    for (int m = 0; m < 2; ++m)
        #pragma unroll
        for (int nt = 0; nt < 4; ++nt) acc[m][nt] = (f32x4){0.f, 0.f, 0.f, 0.f};

    // ---- prologue: cooperatively stage B(0) into buf 0; load A(0) ----
    #pragma unroll
    for (int j = 0; j < 3; ++j) {
        const int i = wv * 3 + j;
        __builtin_amdgcn_global_load_lds((const AS1 void*)(wsrc + i * 64),
                                         (AS3 void*)&lds[0][i][0], 16, 0, 0);
    }
    float4 ac[2][2];
    #pragma unroll
    for (int f = 0; f < 2; ++f) {
        const float* p = arow + (size_t)f * 16 * HIDDEN;
        ac[f][0] = *reinterpret_cast<const float4*>(p);
        ac[f][1] = *reinterpret_cast<const float4*>(p + 4);
    }
    __syncthreads();   // stage(0) drained (vmcnt0) in every wave -> buf0 ready

    for (int kb = 0; kb < KSTEPS; ++kb) {
        const int b = kb & 1;

        // ---- B frags from shared LDS (12 x ds_read, lane-contiguous) ----
        U16x8 B[12];
        #pragma unroll
        for (int i = 0; i < 12; ++i) B[i].u = lds[b][i][lane];

        // ---- stage B(kb+1) into buf b^1 + prefetch A(kb+1) ----
        // WAR on buf b^1 is safe: its readers finished before the barrier at
        // the end of step kb-1 (lgkmcnt(0) drain precedes s_barrier).
        float4 an[2][2];
        if (kb + 1 < KSTEPS) {
            const uint4* ws = wsrc + (size_t)(kb + 1) * (12 * 64);
            #pragma unroll
            for (int j = 0; j < 3; ++j) {
                const int i = wv * 3 + j;
                __builtin_amdgcn_global_load_lds((const AS1 void*)(ws + i * 64),
                                                 (AS3 void*)&lds[b ^ 1][i][0], 16, 0, 0);
            }
            #pragma unroll
            for (int f = 0; f < 2; ++f) {
                const float* p = arow + (size_t)f * 16 * HIDDEN + (size_t)(kb + 1) * 32;
                an[f][0] = *reinterpret_cast<const float4*>(p);
                an[f][1] = *reinterpret_cast<const float4*>(p + 4);
            }
        }

        // ---- compute: 2 m-frags x (split + 24 MFMAs); compiler inserts the
        //      lgkm waits for B and vm waits for A ----
        #pragma unroll
        for (int m = 0; m < 2; ++m) {
            const float a[8] = {ac[m][0].x, ac[m][0].y, ac[m][0].z, ac[m][0].w,
                                ac[m][1].x, ac[m][1].y, ac[m][1].z, ac[m][1].w};
            U16x8 Ah, Am, Al;
            #pragma unroll
            for (int j = 0; j < 4; ++j)
                split2pk(a[2 * j], a[2 * j + 1], Ah.w[j], Am.w[j], Al.w[j]);

            #pragma unroll
            for (int nt = 0; nt < 4; ++nt) {
                acc[m][nt] = __builtin_amdgcn_mfma_f32_16x16x32_bf16(Ah.v, B[0 * 4 + nt].v, acc[m][nt], 0, 0, 0);
                acc[m][nt] = __builtin_amdgcn_mfma_f32_16x16x32_bf16(Ah.v, B[1 * 4 + nt].v, acc[m][nt], 0, 0, 0);
                acc[m][nt] = __builtin_amdgcn_mfma_f32_16x16x32_bf16(Am.v, B[0 * 4 + nt].v, acc[m][nt], 0, 0, 0);
                acc[m][nt] = __builtin_amdgcn_mfma_f32_16x16x32_bf16(Ah.v, B[2 * 4 + nt].v, acc[m][nt], 0, 0, 0);
                acc[m][nt] = __builtin_amdgcn_mfma_f32_16x16x32_bf16(Am.v, B[1 * 4 + nt].v, acc[m][nt], 0, 0, 0);
                acc[m][nt] = __builtin_amdgcn_mfma_f32_16x16x32_bf16(Al.v, B[0 * 4 + nt].v, acc[m][nt], 0, 0, 0);
            }
        }

        if (kb + 1 < KSTEPS) {
            #pragma unroll
            for (int f = 0; f < 2; ++f) { ac[f][0] = an[f][0]; ac[f][1] = an[f][1]; }
        }

        // End-of-step barrier: (a) my stage(kb+1) retired (vmcnt0 drain) so
        // buf b^1 is ready for everyone; (b) everyone's ds_reads of buf b
        // retired (lgkmcnt0) so buf b may be restaged next step.
        __syncthreads();
    }

    // C/D layout (m89-verified): token = t0w + m*16 + q*4 + r, expert = nt*16 + mrow
    float* prow = P + (size_t)ks * TOKENS * NE;
    #pragma unroll
    for (int m = 0; m < 2; ++m)
        #pragma unroll
        for (int nt = 0; nt < 4; ++nt)
            #pragma unroll
            for (int r = 0; r < 4; ++r)
                prow[(size_t)(t0w + m * 16 + q * 4 + r) * NE + nt * 16 + mrow] = acc[m][nt][r];
}

// Finish: sum 4 partials + verified lane=expert epilogue (4 tokens/wave).
__global__ __launch_bounds__(256, 4)
void finish_kernel(const float* __restrict__ P, const float* __restrict__ bg,
                   float* __restrict__ out, float* __restrict__ gf,
                   float* __restrict__ gm)
{
    const int lane = threadIdx.x & 63;
    const int wv   = threadIdx.x >> 6;
    const int tbase = blockIdx.x * 16 + wv * 4;

    __shared__ float fsh[NE], msh[NE];
    if (threadIdx.x < NE) { fsh[threadIdx.x] = 0.f; msh[threadIdx.x] = 0.f; }
    __syncthreads();

    const float bias = bg[lane];
    float f_acc = 0.f, m_acc = 0.f;

    for (int t = 0; t < 4; ++t) {
        const int tok = tbase + t;
        float v = bias;
        #pragma unroll
        for (int sp = 0; sp < KSPLIT; ++sp)
            v += P[((size_t)sp * TOKENS + tok) * NE + lane];

        // top-1 (value desc, index asc — matches lax.top_k tie-break)
        float v1 = v; int i1 = lane;
        #pragma unroll
        for (int off = 32; off > 0; off >>= 1) {
            const float ov = __shfl_xor(v1, off, 64);
            const int   oi = __shfl_xor(i1, off, 64);
            if (ov > v1 || (ov == v1 && oi < i1)) { v1 = ov; i1 = oi; }
        }
        // top-2
        float v2 = (lane == i1) ? -INFINITY : v; int i2 = lane;
        #pragma unroll
        for (int off = 32; off > 0; off >>= 1) {
            const float ov = __shfl_xor(v2, off, 64);
            const int   oi = __shfl_xor(i2, off, 64);
            if (ov > v2 || (ov == v2 && oi < i2)) { v2 = ov; i2 = oi; }
        }

        // full 64-way softmax (for m_i)
        const float e = expf(v - v1);
        float sm = e;
        #pragma unroll
        for (int off = 32; off > 0; off >>= 1) sm += __shfl_xor(sm, off, 64);
        m_acc += e / sm;
        f_acc += ((lane == i1) ? 1.f : 0.f) + ((lane == i2) ? 1.f : 0.f);

        // softmax over top-2 (max v1 already subtracted)
        const float p  = expf(v2 - v1);
        const float s0 = 1.f / (1.f + p);
        const float s1 = p / (1.f + p);

        if (lane == 0) {
            out[IDX_OFF + tok * 2 + 0] = (float)i1;
            out[IDX_OFF + tok * 2 + 1] = (float)i2;
        } else if (lane == 1) {
            out[SC_OFF + tok * 2 + 0] = s0;
            out[SC_OFF + tok * 2 + 1] = s1;
        }
        out[MASK_OFF + (size_t)tok * 2 * NE + lane]      = (lane == i1) ? 1.f : 0.f;
        out[MASK_OFF + (size_t)tok * 2 * NE + NE + lane] = (lane == i2) ? 1.f : 0.f;
    }

    atomicAdd(&fsh[lane], f_acc);
    atomicAdd(&msh[lane], m_acc);
    __syncthreads();
    if (threadIdx.x < NE) {
        atomicAdd(&gf[threadIdx.x], fsh[threadIdx.x]);
        atomicAdd(&gm[threadIdx.x], msh[threadIdx.x]);
    }
}

// aux_loss = 0.01 * sum(f_i * m_i) / 64
__global__ void aux_kernel(const float* __restrict__ gf,
                           const float* __restrict__ gm,
                           float* __restrict__ out)
{
    const int lane = threadIdx.x;
    const float f = gf[lane] / (float)(TOKENS * 2);
    const float m = gm[lane] / (float)TOKENS;
    float p = f * m;
    #pragma unroll
    for (int off = 32; off > 0; off >>= 1) p += __shfl_xor(p, off, 64);
    if (lane == 0) out[AUX_OFF] = 0.01f * p / (float)NE;
}

extern "C" void kernel_launch(void* const* d_in, const int* in_sizes, int n_in,
                              void* d_out, int out_size, void* d_ws, size_t ws_size,
                              hipStream_t stream)
{
    const float* x  = (const float*)d_in[0];
    const float* Wg = (const float*)d_in[1];
    const float* bg = (const float*)d_in[2];
    float* out = (float*)d_out;

    uint4* Wf = (uint4*)d_ws;                         // 1.5 MB split-W frags
    float* P  = (float*)d_ws + (size_t)WF_UINT4 * 4;  // 16.8 MB partials
    float* gf = P + P_FLOATS;
    float* gm = gf + NE;

    hipMemsetAsync(gf, 0, 2 * NE * sizeof(float), stream);

    prep_w<<<KB_TOTAL, 256, 0, stream>>>(Wg, Wf);
    gemm_kernel<<<(TOKENS / 128) * KSPLIT, 256, 0, stream>>>(x, Wf, P);
    finish_kernel<<<TOKENS / 16, 256, 0, stream>>>(P, bg, out, gf, gm);
    aux_kernel<<<1, 64, 0, stream>>>(gf, gm, out);
}